// Round 1
// baseline (159.643 us; speedup 1.0000x reference)
//
#include <hip/hip_runtime.h>
#include <math.h>

#define EDIM 256
#define LDIM 1024
#define HDIM 8
#define DDIM 32

// ---------------------------------------------------------------------------
// proj_kernel: dst(H,L,D) = X(L,E) @ W(E,E)^T, one GEMM per blockIdx.z
// 64x64 output tile per 256-thread block, 4x4 micro-tile per thread.
// LDS tiles stored transposed [e][n] so the inner loop uses float4 reads
// (b128, broadcast across lanes -> conflict-free).
// ---------------------------------------------------------------------------
__global__ __launch_bounds__(256) void proj_kernel(
    const float* __restrict__ Q, const float* __restrict__ Km, const float* __restrict__ V,
    const float* __restrict__ Wq, const float* __restrict__ Wk, const float* __restrict__ Wv,
    float* __restrict__ qT, float* __restrict__ kT, float* __restrict__ vT)
{
    const int z = blockIdx.z;
    const float* __restrict__ X = (z == 0) ? Q : (z == 1) ? Km : V;
    const float* __restrict__ W = (z == 0) ? Wq : (z == 1) ? Wk : Wv;
    float* __restrict__ dst     = (z == 0) ? qT : (z == 1) ? kT : vT;

    const int n0 = blockIdx.x * 64;
    const int o0 = blockIdx.y * 64;
    const int tid = threadIdx.x;
    const int tx = tid & 15, ty = tid >> 4;

    __shared__ float Xs[32][68];   // [e][n], rows 16B-aligned (68*4=272=16*17)
    __shared__ float Ws[32][68];   // [e][o]

    float acc[4][4];
    #pragma unroll
    for (int i = 0; i < 4; ++i)
        #pragma unroll
        for (int j = 0; j < 4; ++j) acc[i][j] = 0.f;

    const int sr = tid >> 2;        // 0..63 (tile row)
    const int sc = (tid & 3) * 8;   // 0,8,16,24 (k-chunk)

    for (int kb = 0; kb < EDIM; kb += 32) {
        float4 a0 = *(const float4*)(X + (n0 + sr) * EDIM + kb + sc);
        float4 a1 = *(const float4*)(X + (n0 + sr) * EDIM + kb + sc + 4);
        float4 b0 = *(const float4*)(W + (o0 + sr) * EDIM + kb + sc);
        float4 b1 = *(const float4*)(W + (o0 + sr) * EDIM + kb + sc + 4);
        __syncthreads();   // protect previous iteration's LDS reads
        Xs[sc+0][sr]=a0.x; Xs[sc+1][sr]=a0.y; Xs[sc+2][sr]=a0.z; Xs[sc+3][sr]=a0.w;
        Xs[sc+4][sr]=a1.x; Xs[sc+5][sr]=a1.y; Xs[sc+6][sr]=a1.z; Xs[sc+7][sr]=a1.w;
        Ws[sc+0][sr]=b0.x; Ws[sc+1][sr]=b0.y; Ws[sc+2][sr]=b0.z; Ws[sc+3][sr]=b0.w;
        Ws[sc+4][sr]=b1.x; Ws[sc+5][sr]=b1.y; Ws[sc+6][sr]=b1.z; Ws[sc+7][sr]=b1.w;
        __syncthreads();
        #pragma unroll
        for (int e = 0; e < 32; ++e) {
            float4 xr = *(const float4*)&Xs[e][ty*4];
            float4 wr = *(const float4*)&Ws[e][tx*4];
            acc[0][0] += xr.x*wr.x; acc[0][1] += xr.x*wr.y; acc[0][2] += xr.x*wr.z; acc[0][3] += xr.x*wr.w;
            acc[1][0] += xr.y*wr.x; acc[1][1] += xr.y*wr.y; acc[1][2] += xr.y*wr.z; acc[1][3] += xr.y*wr.w;
            acc[2][0] += xr.z*wr.x; acc[2][1] += xr.z*wr.y; acc[2][2] += xr.z*wr.z; acc[2][3] += xr.z*wr.w;
            acc[3][0] += xr.w*wr.x; acc[3][1] += xr.w*wr.y; acc[3][2] += xr.w*wr.z; acc[3][3] += xr.w*wr.w;
        }
    }

    // write to (H, L, D): o = o0 + tx*4 + j; h = o/32, d = o%32 (4 j's stay in one h)
    const int h  = (o0 >> 5) + (tx >> 3);
    const int d0 = (tx & 7) * 4;
    #pragma unroll
    for (int i = 0; i < 4; ++i) {
        const int n = n0 + ty*4 + i;
        float4 r; r.x = acc[i][0]; r.y = acc[i][1]; r.z = acc[i][2]; r.w = acc[i][3];
        *(float4*)(dst + h*(LDIM*DDIM) + n*DDIM + d0) = r;
    }
}

// ---------------------------------------------------------------------------
// coeff_kernel: coeff[h][n] = sum_d q[n,h,d] * Wr[h*32+d]
// ---------------------------------------------------------------------------
__global__ __launch_bounds__(256) void coeff_kernel(
    const float* __restrict__ qT, const float* __restrict__ Wr, float* __restrict__ coeff)
{
    const int idx = blockIdx.x * 256 + threadIdx.x;   // 0..8191
    const int h = idx >> 10;
    const int n = idx & 1023;
    const float* qp = qT + h*(LDIM*DDIM) + n*DDIM;
    const float* wp = Wr + h*DDIM;
    float s = 0.f;
    #pragma unroll
    for (int d = 0; d < DDIM; ++d) s += qp[d] * wp[d];
    coeff[h*LDIM + n] = s;
}

// ---------------------------------------------------------------------------
// attn_kernel: flash-style online softmax. One block per (h, 32 q-rows).
// 256 threads: tx = tid&15 (k / d direction), ty = tid>>4 (q rows ty*2..+1).
// energy = (q.k + coeff[h,q]*log(|pq-pk|+1)) / 16
// ---------------------------------------------------------------------------
__global__ __launch_bounds__(256) void attn_kernel(
    const float* __restrict__ qT, const float* __restrict__ kT, const float* __restrict__ vT,
    const float* __restrict__ coeff, const float* __restrict__ pos, float* __restrict__ A)
{
    const int h  = blockIdx.y;
    const int q0 = blockIdx.x * 32;
    const int tid = threadIdx.x;
    const int tx = tid & 15, ty = tid >> 4;

    __shared__ float qs[32][34];   // [d][r] transposed, rows 8B-aligned
    __shared__ float ks[32][64];   // [d][c] transposed, rows 16B-aligned
    __shared__ float vs[64][32];   // [c][d] row-major
    __shared__ float ps[32][65];   // [r][c] padded -> conflict-free column reads
    __shared__ float pk[64];
    __shared__ float pqs[32];
    __shared__ float cqs[32];

    // stage q tile (transposed) + per-row pos/coeff
    {
        const int r = tid >> 3;          // 0..31
        const int c = (tid & 7) * 4;     // 0..28
        float4 a = *(const float4*)(qT + (h*LDIM + q0 + r) * DDIM + c);
        qs[c+0][r] = a.x; qs[c+1][r] = a.y; qs[c+2][r] = a.z; qs[c+3][r] = a.w;
        if (tid < 32) {
            pqs[tid] = pos[q0 + tid];
            cqs[tid] = coeff[h*LDIM + q0 + tid] * 0.0625f;  // pre-divide by sqrt(E)=16
        }
    }
    __syncthreads();

    const int r0 = ty*2, r1 = ty*2 + 1;
    const float pq0 = pqs[r0], pq1 = pqs[r1];
    const float cq0 = cqs[r0], cq1 = cqs[r1];
    const int dc = tx*2;

    float m0 = -INFINITY, m1 = -INFINITY;
    float l0 = 0.f, l1 = 0.f;
    float o00 = 0.f, o01 = 0.f, o10 = 0.f, o11 = 0.f;
    const float inv = 0.0625f;

    for (int kt = 0; kt < LDIM; kt += 64) {
        // ---- stage k (transposed), v (row-major), pk ----
        {
            const int c = tid >> 2;          // 0..63
            const int d = (tid & 3) * 8;     // 0,8,16,24
            const float* kp = kT + (h*LDIM + kt + c) * DDIM + d;
            float4 a0 = *(const float4*)kp;
            float4 a1 = *(const float4*)(kp + 4);
            const float* vp = vT + (h*LDIM + kt + c) * DDIM + d;
            float4 b0 = *(const float4*)vp;
            float4 b1 = *(const float4*)(vp + 4);
            __syncthreads();   // previous tile's LDS reads done before overwrite
            ks[d+0][c]=a0.x; ks[d+1][c]=a0.y; ks[d+2][c]=a0.z; ks[d+3][c]=a0.w;
            ks[d+4][c]=a1.x; ks[d+5][c]=a1.y; ks[d+6][c]=a1.z; ks[d+7][c]=a1.w;
            *(float4*)&vs[c][d]   = b0;
            *(float4*)&vs[c][d+4] = b1;
            if (tid < 64) pk[tid] = pos[kt + tid];
        }
        __syncthreads();

        // ---- scores S[2][4] ----
        float s00=0.f,s01=0.f,s02=0.f,s03=0.f, s10=0.f,s11=0.f,s12=0.f,s13=0.f;
        #pragma unroll
        for (int d = 0; d < 32; ++d) {
            float2 q2 = *(const float2*)&qs[d][r0];
            float4 k4 = *(const float4*)&ks[d][tx*4];
            s00 += q2.x*k4.x; s01 += q2.x*k4.y; s02 += q2.x*k4.z; s03 += q2.x*k4.w;
            s10 += q2.y*k4.x; s11 += q2.y*k4.y; s12 += q2.y*k4.z; s13 += q2.y*k4.w;
        }

        // ---- relative-position bias ----
        const float p0 = pk[tx*4+0], p1 = pk[tx*4+1], p2 = pk[tx*4+2], p3 = pk[tx*4+3];
        s00 = fmaf(s00, inv, cq0 * logf(fabsf(pq0 - p0) + 1.f));
        s01 = fmaf(s01, inv, cq0 * logf(fabsf(pq0 - p1) + 1.f));
        s02 = fmaf(s02, inv, cq0 * logf(fabsf(pq0 - p2) + 1.f));
        s03 = fmaf(s03, inv, cq0 * logf(fabsf(pq0 - p3) + 1.f));
        s10 = fmaf(s10, inv, cq1 * logf(fabsf(pq1 - p0) + 1.f));
        s11 = fmaf(s11, inv, cq1 * logf(fabsf(pq1 - p1) + 1.f));
        s12 = fmaf(s12, inv, cq1 * logf(fabsf(pq1 - p2) + 1.f));
        s13 = fmaf(s13, inv, cq1 * logf(fabsf(pq1 - p3) + 1.f));

        // ---- online softmax (row reduce across the 16-lane tx group) ----
        float m0t = fmaxf(fmaxf(s00, s01), fmaxf(s02, s03));
        float m1t = fmaxf(fmaxf(s10, s11), fmaxf(s12, s13));
        #pragma unroll
        for (int off = 1; off < 16; off <<= 1) {
            m0t = fmaxf(m0t, __shfl_xor(m0t, off, 64));
            m1t = fmaxf(m1t, __shfl_xor(m1t, off, 64));
        }
        const float mn0 = fmaxf(m0, m0t), mn1 = fmaxf(m1, m1t);
        const float al0 = expf(m0 - mn0), al1 = expf(m1 - mn1);
        m0 = mn0; m1 = mn1;
        s00 = expf(s00 - mn0); s01 = expf(s01 - mn0); s02 = expf(s02 - mn0); s03 = expf(s03 - mn0);
        s10 = expf(s10 - mn1); s11 = expf(s11 - mn1); s12 = expf(s12 - mn1); s13 = expf(s13 - mn1);
        float t0 = (s00 + s01) + (s02 + s03);
        float t1 = (s10 + s11) + (s12 + s13);
        #pragma unroll
        for (int off = 1; off < 16; off <<= 1) {
            t0 += __shfl_xor(t0, off, 64);
            t1 += __shfl_xor(t1, off, 64);
        }
        l0 = l0*al0 + t0;  l1 = l1*al1 + t1;
        o00 *= al0; o01 *= al0; o10 *= al1; o11 *= al1;

        ps[r0][tx*4+0] = s00; ps[r0][tx*4+1] = s01; ps[r0][tx*4+2] = s02; ps[r0][tx*4+3] = s03;
        ps[r1][tx*4+0] = s10; ps[r1][tx*4+1] = s11; ps[r1][tx*4+2] = s12; ps[r1][tx*4+3] = s13;
        __syncthreads();

        // ---- PV: O[r][dc..dc+1] += sum_c P[r][c] * V[c][dc..dc+1] ----
        #pragma unroll 8
        for (int c = 0; c < 64; ++c) {
            const float pa = ps[r0][c], pb = ps[r1][c];
            float2 v2 = *(const float2*)&vs[c][dc];
            o00 += pa*v2.x; o01 += pa*v2.y;
            o10 += pb*v2.x; o11 += pb*v2.y;
        }
        // next iteration's first __syncthreads() protects vs/ks/ps reuse
    }

    // ---- normalize + write A (L, E) row-major, e = h*32 + d ----
    float2 w0; w0.x = o00 / l0; w0.y = o01 / l0;
    float2 w1; w1.x = o10 / l1; w1.y = o11 / l1;
    *(float2*)(A + (q0 + r0)*EDIM + h*DDIM + dc) = w0;
    *(float2*)(A + (q0 + r1)*EDIM + h*DDIM + dc) = w1;
}

// ---------------------------------------------------------------------------
// outproj_kernel: out(L,E) = A(L,E) @ Wo(E,E)^T + bo
// ---------------------------------------------------------------------------
__global__ __launch_bounds__(256) void outproj_kernel(
    const float* __restrict__ Aa, const float* __restrict__ Wo,
    const float* __restrict__ bo, float* __restrict__ out)
{
    const int n0 = blockIdx.x * 64;
    const int o0 = blockIdx.y * 64;
    const int tid = threadIdx.x;
    const int tx = tid & 15, ty = tid >> 4;

    __shared__ float Xs[32][68];
    __shared__ float Ws[32][68];

    float acc[4][4];
    #pragma unroll
    for (int i = 0; i < 4; ++i)
        #pragma unroll
        for (int j = 0; j < 4; ++j) acc[i][j] = 0.f;

    const int sr = tid >> 2;
    const int sc = (tid & 3) * 8;

    for (int kb = 0; kb < EDIM; kb += 32) {
        float4 a0 = *(const float4*)(Aa + (n0 + sr) * EDIM + kb + sc);
        float4 a1 = *(const float4*)(Aa + (n0 + sr) * EDIM + kb + sc + 4);
        float4 b0 = *(const float4*)(Wo + (o0 + sr) * EDIM + kb + sc);
        float4 b1 = *(const float4*)(Wo + (o0 + sr) * EDIM + kb + sc + 4);
        __syncthreads();
        Xs[sc+0][sr]=a0.x; Xs[sc+1][sr]=a0.y; Xs[sc+2][sr]=a0.z; Xs[sc+3][sr]=a0.w;
        Xs[sc+4][sr]=a1.x; Xs[sc+5][sr]=a1.y; Xs[sc+6][sr]=a1.z; Xs[sc+7][sr]=a1.w;
        Ws[sc+0][sr]=b0.x; Ws[sc+1][sr]=b0.y; Ws[sc+2][sr]=b0.z; Ws[sc+3][sr]=b0.w;
        Ws[sc+4][sr]=b1.x; Ws[sc+5][sr]=b1.y; Ws[sc+6][sr]=b1.z; Ws[sc+7][sr]=b1.w;
        __syncthreads();
        #pragma unroll
        for (int e = 0; e < 32; ++e) {
            float4 xr = *(const float4*)&Xs[e][ty*4];
            float4 wr = *(const float4*)&Ws[e][tx*4];
            acc[0][0] += xr.x*wr.x; acc[0][1] += xr.x*wr.y; acc[0][2] += xr.x*wr.z; acc[0][3] += xr.x*wr.w;
            acc[1][0] += xr.y*wr.x; acc[1][1] += xr.y*wr.y; acc[1][2] += xr.y*wr.z; acc[1][3] += xr.y*wr.w;
            acc[2][0] += xr.z*wr.x; acc[2][1] += xr.z*wr.y; acc[2][2] += xr.z*wr.z; acc[2][3] += xr.z*wr.w;
            acc[3][0] += xr.w*wr.x; acc[3][1] += xr.w*wr.y; acc[3][2] += xr.w*wr.z; acc[3][3] += xr.w*wr.w;
        }
    }

    const int o = o0 + tx*4;
    float4 bias = *(const float4*)(bo + o);
    #pragma unroll
    for (int i = 0; i < 4; ++i) {
        const int n = n0 + ty*4 + i;
        float4 r;
        r.x = acc[i][0] + bias.x; r.y = acc[i][1] + bias.y;
        r.z = acc[i][2] + bias.z; r.w = acc[i][3] + bias.w;
        *(float4*)(out + n*EDIM + o) = r;
    }
}

// ---------------------------------------------------------------------------
extern "C" void kernel_launch(void* const* d_in, const int* in_sizes, int n_in,
                              void* d_out, int out_size, void* d_ws, size_t ws_size,
                              hipStream_t stream) {
    const float* V   = (const float*)d_in[0];
    const float* K   = (const float*)d_in[1];
    const float* Q   = (const float*)d_in[2];
    const float* pos = (const float*)d_in[3];
    const float* Wq  = (const float*)d_in[4];
    const float* Wk  = (const float*)d_in[5];
    const float* Wv  = (const float*)d_in[6];
    const float* Wr  = (const float*)d_in[7];
    const float* Wo  = (const float*)d_in[8];
    const float* bo  = (const float*)d_in[9];
    float* out = (float*)d_out;
    float* ws  = (float*)d_ws;

    // workspace layout (floats): qT/kT/vT are (H,L,D)=262144 each,
    // coeff (H,L)=8192, A (L,E)=262144. Total ~4.03 MB.
    float* qT    = ws;
    float* kT    = ws + 262144;
    float* vT    = ws + 524288;
    float* coeff = ws + 786432;
    float* A     = ws + 794624;

    proj_kernel   <<<dim3(16, 4, 3), 256, 0, stream>>>(Q, K, V, Wq, Wk, Wv, qT, kT, vT);
    coeff_kernel  <<<dim3(32),       256, 0, stream>>>(qT, Wr, coeff);
    attn_kernel   <<<dim3(32, 8),    256, 0, stream>>>(qT, kT, vT, coeff, pos, A);
    outproj_kernel<<<dim3(16, 4),    256, 0, stream>>>(A, Wo, bo, out);
}

// Round 2
// 149.904 us; speedup vs baseline: 1.0650x; 1.0650x over previous
//
#include <hip/hip_runtime.h>
#include <math.h>

#define EDIM 256
#define LDIM 1024
#define HDIM 8
#define DDIM 32

// ---------------------------------------------------------------------------
// proj_kernel: dst(H,L,D) = X(L,E) @ W(E,E)^T, one GEMM per blockIdx.z
// 64x64 output tile, 4x4 micro-tile. LDS transposed [e][n], stride 66 so the
// scalar staging writes are 2-way (free); reads are float2 pairs (8B aligned).
// z==0 additionally computes coeff[h][n] = sum_d q[n,h,d]*Wr[h*32+d] in the
// epilogue (shuffle-reduce over the 8 lanes covering d).
// ---------------------------------------------------------------------------
__global__ __launch_bounds__(256) void proj_kernel(
    const float* __restrict__ Q, const float* __restrict__ Km, const float* __restrict__ V,
    const float* __restrict__ Wq, const float* __restrict__ Wk, const float* __restrict__ Wv,
    const float* __restrict__ Wr,
    float* __restrict__ qT, float* __restrict__ kT, float* __restrict__ vT,
    float* __restrict__ coeff)
{
    const int z = blockIdx.z;
    const float* __restrict__ X = (z == 0) ? Q : (z == 1) ? Km : V;
    const float* __restrict__ W = (z == 0) ? Wq : (z == 1) ? Wk : Wv;
    float* __restrict__ dst     = (z == 0) ? qT : (z == 1) ? kT : vT;

    const int n0 = blockIdx.x * 64;
    const int o0 = blockIdx.y * 64;
    const int tid = threadIdx.x;
    const int tx = tid & 15, ty = tid >> 4;

    __shared__ float Xs[32][66];   // [e][n]
    __shared__ float Ws[32][66];   // [e][o]

    float acc[4][4];
    #pragma unroll
    for (int i = 0; i < 4; ++i)
        #pragma unroll
        for (int j = 0; j < 4; ++j) acc[i][j] = 0.f;

    const int sr = tid >> 2;        // 0..63 (tile row)
    const int sc = (tid & 3) * 8;   // 0,8,16,24 (k-chunk)

    for (int kb = 0; kb < EDIM; kb += 32) {
        float4 a0 = *(const float4*)(X + (n0 + sr) * EDIM + kb + sc);
        float4 a1 = *(const float4*)(X + (n0 + sr) * EDIM + kb + sc + 4);
        float4 b0 = *(const float4*)(W + (o0 + sr) * EDIM + kb + sc);
        float4 b1 = *(const float4*)(W + (o0 + sr) * EDIM + kb + sc + 4);
        __syncthreads();   // previous iteration's LDS reads done
        Xs[sc+0][sr]=a0.x; Xs[sc+1][sr]=a0.y; Xs[sc+2][sr]=a0.z; Xs[sc+3][sr]=a0.w;
        Xs[sc+4][sr]=a1.x; Xs[sc+5][sr]=a1.y; Xs[sc+6][sr]=a1.z; Xs[sc+7][sr]=a1.w;
        Ws[sc+0][sr]=b0.x; Ws[sc+1][sr]=b0.y; Ws[sc+2][sr]=b0.z; Ws[sc+3][sr]=b0.w;
        Ws[sc+4][sr]=b1.x; Ws[sc+5][sr]=b1.y; Ws[sc+6][sr]=b1.z; Ws[sc+7][sr]=b1.w;
        __syncthreads();
        #pragma unroll
        for (int e = 0; e < 32; ++e) {
            float2 xa = *(const float2*)&Xs[e][ty*4];
            float2 xb = *(const float2*)&Xs[e][ty*4+2];
            float2 wa = *(const float2*)&Ws[e][tx*4];
            float2 wb = *(const float2*)&Ws[e][tx*4+2];
            acc[0][0] += xa.x*wa.x; acc[0][1] += xa.x*wa.y; acc[0][2] += xa.x*wb.x; acc[0][3] += xa.x*wb.y;
            acc[1][0] += xa.y*wa.x; acc[1][1] += xa.y*wa.y; acc[1][2] += xa.y*wb.x; acc[1][3] += xa.y*wb.y;
            acc[2][0] += xb.x*wa.x; acc[2][1] += xb.x*wa.y; acc[2][2] += xb.x*wb.x; acc[2][3] += xb.x*wb.y;
            acc[3][0] += xb.y*wa.x; acc[3][1] += xb.y*wa.y; acc[3][2] += xb.y*wb.x; acc[3][3] += xb.y*wb.y;
        }
    }

    // write to (H, L, D)
    const int h  = (o0 >> 5) + (tx >> 3);
    const int d0 = (tx & 7) * 4;
    #pragma unroll
    for (int i = 0; i < 4; ++i) {
        const int n = n0 + ty*4 + i;
        float4 r; r.x = acc[i][0]; r.y = acc[i][1]; r.z = acc[i][2]; r.w = acc[i][3];
        *(float4*)(dst + h*(LDIM*DDIM) + n*DDIM + d0) = r;
    }

    // fused coeff epilogue (q projection only)
    if (z == 0) {
        const int o = o0 + tx*4;
        const float wr0 = Wr[o+0], wr1 = Wr[o+1], wr2 = Wr[o+2], wr3 = Wr[o+3];
        #pragma unroll
        for (int i = 0; i < 4; ++i) {
            float c = acc[i][0]*wr0 + acc[i][1]*wr1 + acc[i][2]*wr2 + acc[i][3]*wr3;
            c += __shfl_xor(c, 1, 64);
            c += __shfl_xor(c, 2, 64);
            c += __shfl_xor(c, 4, 64);
            if ((tx & 7) == 0) coeff[h*LDIM + n0 + ty*4 + i] = c;
        }
    }
}

// ---------------------------------------------------------------------------
// attn_kernel: flash-style online softmax with K-split partials.
// Grid (32, H, P): block handles (h, 32 q-rows, nkt k-tiles of 64 starting at
// part p). Writes UNNORMALIZED O plus per-row (m, l); combine happens in
// outproj staging. 256 threads: tx = tid&15 (4 k-cols), ty = tid>>4 (2 rows).
// ---------------------------------------------------------------------------
__global__ __launch_bounds__(256) void attn_kernel(
    const float* __restrict__ qT, const float* __restrict__ kT, const float* __restrict__ vT,
    const float* __restrict__ coeff, const float* __restrict__ pos,
    float* __restrict__ Op, float* __restrict__ Mp, float* __restrict__ Lp, int nkt)
{
    const int h  = blockIdx.y;
    const int q0 = blockIdx.x * 32;
    const int p  = blockIdx.z;
    const int kt0 = p * nkt * 64;
    const int tid = threadIdx.x;
    const int tx = tid & 15, ty = tid >> 4;

    __shared__ float qs[32][34];   // [d][r]
    __shared__ float ks[32][66];   // [d][c], stride 66: 2-way writes, aligned float2 reads
    __shared__ float vs[64][36];   // [c][d], stride 36: 2-way float4 writes
    __shared__ float ps[32][65];   // [r][c]
    __shared__ float pk[64];
    __shared__ float pqs[32];
    __shared__ float cqs[32];

    {
        const int r = tid >> 3;          // 0..31
        const int c = (tid & 7) * 4;     // 0..28
        float4 a = *(const float4*)(qT + (h*LDIM + q0 + r) * DDIM + c);
        qs[c+0][r] = a.x; qs[c+1][r] = a.y; qs[c+2][r] = a.z; qs[c+3][r] = a.w;
        if (tid < 32) {
            pqs[tid] = pos[q0 + tid];
            cqs[tid] = coeff[h*LDIM + q0 + tid] * 0.0625f;  // pre-divide by sqrt(E)
        }
    }
    __syncthreads();

    const int r0 = ty*2, r1 = ty*2 + 1;
    const float pq0 = pqs[r0], pq1 = pqs[r1];
    const float cq0 = cqs[r0], cq1 = cqs[r1];
    const int dc = tx*2;

    float m0 = -INFINITY, m1 = -INFINITY;
    float l0 = 0.f, l1 = 0.f;
    float o00 = 0.f, o01 = 0.f, o10 = 0.f, o11 = 0.f;
    const float inv = 0.0625f;

    for (int t = 0; t < nkt; ++t) {
        const int kt = kt0 + t * 64;
        {
            const int c = tid >> 2;          // 0..63
            const int d = (tid & 3) * 8;     // 0,8,16,24
            const float* kp = kT + (h*LDIM + kt + c) * DDIM + d;
            float4 a0 = *(const float4*)kp;
            float4 a1 = *(const float4*)(kp + 4);
            const float* vp = vT + (h*LDIM + kt + c) * DDIM + d;
            float4 b0 = *(const float4*)vp;
            float4 b1 = *(const float4*)(vp + 4);
            __syncthreads();
            ks[d+0][c]=a0.x; ks[d+1][c]=a0.y; ks[d+2][c]=a0.z; ks[d+3][c]=a0.w;
            ks[d+4][c]=a1.x; ks[d+5][c]=a1.y; ks[d+6][c]=a1.z; ks[d+7][c]=a1.w;
            *(float4*)&vs[c][d]   = b0;
            *(float4*)&vs[c][d+4] = b1;
            if (tid < 64) pk[tid] = pos[kt + tid];
        }
        __syncthreads();

        float s00=0.f,s01=0.f,s02=0.f,s03=0.f, s10=0.f,s11=0.f,s12=0.f,s13=0.f;
        #pragma unroll
        for (int d = 0; d < 32; ++d) {
            float2 q2 = *(const float2*)&qs[d][r0];
            float2 ka = *(const float2*)&ks[d][tx*4];
            float2 kb = *(const float2*)&ks[d][tx*4+2];
            s00 += q2.x*ka.x; s01 += q2.x*ka.y; s02 += q2.x*kb.x; s03 += q2.x*kb.y;
            s10 += q2.y*ka.x; s11 += q2.y*ka.y; s12 += q2.y*kb.x; s13 += q2.y*kb.y;
        }

        const float p0 = pk[tx*4+0], p1 = pk[tx*4+1], p2 = pk[tx*4+2], p3 = pk[tx*4+3];
        s00 = fmaf(s00, inv, cq0 * logf(fabsf(pq0 - p0) + 1.f));
        s01 = fmaf(s01, inv, cq0 * logf(fabsf(pq0 - p1) + 1.f));
        s02 = fmaf(s02, inv, cq0 * logf(fabsf(pq0 - p2) + 1.f));
        s03 = fmaf(s03, inv, cq0 * logf(fabsf(pq0 - p3) + 1.f));
        s10 = fmaf(s10, inv, cq1 * logf(fabsf(pq1 - p0) + 1.f));
        s11 = fmaf(s11, inv, cq1 * logf(fabsf(pq1 - p1) + 1.f));
        s12 = fmaf(s12, inv, cq1 * logf(fabsf(pq1 - p2) + 1.f));
        s13 = fmaf(s13, inv, cq1 * logf(fabsf(pq1 - p3) + 1.f));

        float m0t = fmaxf(fmaxf(s00, s01), fmaxf(s02, s03));
        float m1t = fmaxf(fmaxf(s10, s11), fmaxf(s12, s13));
        #pragma unroll
        for (int off = 1; off < 16; off <<= 1) {
            m0t = fmaxf(m0t, __shfl_xor(m0t, off, 64));
            m1t = fmaxf(m1t, __shfl_xor(m1t, off, 64));
        }
        const float mn0 = fmaxf(m0, m0t), mn1 = fmaxf(m1, m1t);
        const float al0 = expf(m0 - mn0), al1 = expf(m1 - mn1);
        m0 = mn0; m1 = mn1;
        s00 = expf(s00 - mn0); s01 = expf(s01 - mn0); s02 = expf(s02 - mn0); s03 = expf(s03 - mn0);
        s10 = expf(s10 - mn1); s11 = expf(s11 - mn1); s12 = expf(s12 - mn1); s13 = expf(s13 - mn1);
        float t0 = (s00 + s01) + (s02 + s03);
        float t1 = (s10 + s11) + (s12 + s13);
        #pragma unroll
        for (int off = 1; off < 16; off <<= 1) {
            t0 += __shfl_xor(t0, off, 64);
            t1 += __shfl_xor(t1, off, 64);
        }
        l0 = l0*al0 + t0;  l1 = l1*al1 + t1;
        o00 *= al0; o01 *= al0; o10 *= al1; o11 *= al1;

        ps[r0][tx*4+0] = s00; ps[r0][tx*4+1] = s01; ps[r0][tx*4+2] = s02; ps[r0][tx*4+3] = s03;
        ps[r1][tx*4+0] = s10; ps[r1][tx*4+1] = s11; ps[r1][tx*4+2] = s12; ps[r1][tx*4+3] = s13;
        __syncthreads();

        #pragma unroll 8
        for (int c = 0; c < 64; ++c) {
            const float pa = ps[r0][c], pb = ps[r1][c];
            float2 v2 = *(const float2*)&vs[c][dc];
            o00 += pa*v2.x; o01 += pa*v2.y;
            o10 += pb*v2.x; o11 += pb*v2.y;
        }
    }

    // unnormalized partial output + (m, l)
    const int ph = p * HDIM + h;
    float2 w0; w0.x = o00; w0.y = o01;
    float2 w1; w1.x = o10; w1.y = o11;
    *(float2*)(Op + (ph*LDIM + q0 + r0)*DDIM + dc) = w0;
    *(float2*)(Op + (ph*LDIM + q0 + r1)*DDIM + dc) = w1;
    if (tx == 0) {
        Mp[ph*LDIM + q0 + r0] = m0;  Lp[ph*LDIM + q0 + r0] = l0;
        Mp[ph*LDIM + q0 + r1] = m1;  Lp[ph*LDIM + q0 + r1] = l1;
    }
}

// ---------------------------------------------------------------------------
// outproj_kernel: out(L,E) = A(L,E) @ Wo(E,E)^T + bo, where A is reconstructed
// on the fly from the P attention partials (combine fused into staging).
// 32x32 tiles -> grid (32, 8) = 256 blocks. micro 2x2.
// ---------------------------------------------------------------------------
__global__ __launch_bounds__(256) void outproj_kernel(
    const float* __restrict__ Op, const float* __restrict__ Mp, const float* __restrict__ Lp,
    int P, const float* __restrict__ Wo, const float* __restrict__ bo, float* __restrict__ out)
{
    const int n0 = blockIdx.x * 32;
    const int o0 = blockIdx.y * 32;
    const int tid = threadIdx.x;
    const int tx = tid & 15, ty = tid >> 4;

    __shared__ float  Xs[32][34];   // [e][n] (e local to the 32-chunk = one head)
    __shared__ float  Ws[32][34];   // [e][o]
    __shared__ float4 scl[32];      // per-row combine scales a_p / sum(a_p l_p)

    float acc[2][2] = {{0.f,0.f},{0.f,0.f}};

    const int sn = tid >> 3;         // 0..31 (row within tile)
    const int sc4 = (tid & 7) * 4;   // 0..28 (d / e chunk)

    for (int kb = 0; kb < EDIM; kb += 32) {
        const int h = kb >> 5;
        // --- per-row combine scales (rows n0..n0+31 for head h) ---
        if (tid < 32) {
            const int n = n0 + tid;
            float m[4], l[4], a[4];
            float mx = -INFINITY;
            #pragma unroll
            for (int p = 0; p < 4; ++p) {
                if (p < P) {
                    m[p] = Mp[(p*HDIM + h)*LDIM + n];
                    l[p] = Lp[(p*HDIM + h)*LDIM + n];
                    mx = fmaxf(mx, m[p]);
                }
            }
            float s = 0.f;
            #pragma unroll
            for (int p = 0; p < 4; ++p) {
                if (p < P) { a[p] = expf(m[p] - mx); s += a[p] * l[p]; }
            }
            const float inv = 1.f / s;
            float4 r; r.x = r.y = r.z = r.w = 0.f;
            r.x = a[0] * inv;
            if (P > 1) r.y = a[1] * inv;
            if (P > 2) { r.z = a[2] * inv; r.w = a[3] * inv; }
            scl[tid] = r;
        }
        __syncthreads();   // scl ready; also: previous iter's inner-loop reads done

        // --- staging: combined A chunk + Wo chunk, transposed into LDS ---
        {
            const float4 s4 = scl[sn];
            const float* ob = Op + (h*LDIM + n0 + sn)*DDIM + sc4;
            float4 x0 = *(const float4*)ob;
            float4 x; x.x = s4.x*x0.x; x.y = s4.x*x0.y; x.z = s4.x*x0.z; x.w = s4.x*x0.w;
            if (P > 1) {
                float4 x1 = *(const float4*)(ob + 1*HDIM*LDIM*DDIM);
                x.x += s4.y*x1.x; x.y += s4.y*x1.y; x.z += s4.y*x1.z; x.w += s4.y*x1.w;
            }
            if (P > 2) {
                float4 x2 = *(const float4*)(ob + 2*HDIM*LDIM*DDIM);
                float4 x3 = *(const float4*)(ob + 3*HDIM*LDIM*DDIM);
                x.x += s4.z*x2.x + s4.w*x3.x; x.y += s4.z*x2.y + s4.w*x3.y;
                x.z += s4.z*x2.z + s4.w*x3.z; x.w += s4.z*x2.w + s4.w*x3.w;
            }
            float4 w = *(const float4*)(Wo + (o0 + sn)*EDIM + kb + sc4);
            Xs[sc4+0][sn]=x.x; Xs[sc4+1][sn]=x.y; Xs[sc4+2][sn]=x.z; Xs[sc4+3][sn]=x.w;
            Ws[sc4+0][sn]=w.x; Ws[sc4+1][sn]=w.y; Ws[sc4+2][sn]=w.z; Ws[sc4+3][sn]=w.w;
        }
        __syncthreads();

        #pragma unroll
        for (int e = 0; e < 32; ++e) {
            float2 x2 = *(const float2*)&Xs[e][ty*2];
            float2 w2 = *(const float2*)&Ws[e][tx*2];
            acc[0][0] += x2.x*w2.x; acc[0][1] += x2.x*w2.y;
            acc[1][0] += x2.y*w2.x; acc[1][1] += x2.y*w2.y;
        }
    }

    const int o = o0 + tx*2;
    float2 bias = *(const float2*)(bo + o);
    #pragma unroll
    for (int i = 0; i < 2; ++i) {
        const int n = n0 + ty*2 + i;
        float2 r; r.x = acc[i][0] + bias.x; r.y = acc[i][1] + bias.y;
        *(float2*)(out + n*EDIM + o) = r;
    }
}

// ---------------------------------------------------------------------------
extern "C" void kernel_launch(void* const* d_in, const int* in_sizes, int n_in,
                              void* d_out, int out_size, void* d_ws, size_t ws_size,
                              hipStream_t stream) {
    const float* V   = (const float*)d_in[0];
    const float* K   = (const float*)d_in[1];
    const float* Q   = (const float*)d_in[2];
    const float* pos = (const float*)d_in[3];
    const float* Wq  = (const float*)d_in[4];
    const float* Wk  = (const float*)d_in[5];
    const float* Wv  = (const float*)d_in[6];
    const float* Wr  = (const float*)d_in[7];
    const float* Wo  = (const float*)d_in[8];
    const float* bo  = (const float*)d_in[9];
    float* out = (float*)d_out;
    float* ws  = (float*)d_ws;

    // pick K-split factor P by available workspace
    // floats needed: 3*262144 (qT/kT/vT) + 8192 (coeff) + P*(262144 + 2*8192)
    auto need = [](int P) -> size_t {
        return (size_t)(3*262144 + 8192 + P*(262144 + 2*8192)) * 4;
    };
    int P = 1;
    if (ws_size >= need(4)) P = 4;
    else if (ws_size >= need(2)) P = 2;

    float* qT    = ws;
    float* kT    = ws + 262144;
    float* vT    = ws + 524288;
    float* coeff = ws + 786432;
    float* Op    = ws + 794624;                 // P * (8*1024*32)
    float* Mp    = Op + (size_t)P * 262144;     // P * 8192
    float* Lp    = Mp + (size_t)P * 8192;

    proj_kernel   <<<dim3(16, 4, 3),  256, 0, stream>>>(Q, K, V, Wq, Wk, Wv, Wr, qT, kT, vT, coeff);
    attn_kernel   <<<dim3(32, 8, P),  256, 0, stream>>>(qT, kT, vT, coeff, pos, Op, Mp, Lp, 16 / P);
    outproj_kernel<<<dim3(32, 8),     256, 0, stream>>>(Op, Mp, Lp, P, Wo, bo, out);
}

// Round 3
// 148.425 us; speedup vs baseline: 1.0756x; 1.0100x over previous
//
#include <hip/hip_runtime.h>
#include <math.h>

#define EDIM 256
#define LDIM 1024
#define HDIM 8
#define DDIM 32

typedef __attribute__((ext_vector_type(8))) short short8;
typedef __attribute__((ext_vector_type(4))) float f32x4;

__device__ inline unsigned short bf16h(float x) {
    unsigned u = __float_as_uint(x);
    return (unsigned short)((u + 0x7fff + ((u >> 16) & 1)) >> 16);   // RNE
}
__device__ inline float bf16tof(unsigned short h) {
    return __uint_as_float(((unsigned)h) << 16);
}

// ---------------------------------------------------------------------------
// proj_kernel: dst(H,L,D) = X(L,E) @ W(E,E)^T, one GEMM per blockIdx.z
// 64x64 tile, 4x4 micro, LDS [e][n] stride 68 (16B-aligned float4 reads).
// z==0 fuses coeff[h][n] = sum_d q[n,h,d]*Wr[h*32+d].
// ---------------------------------------------------------------------------
__global__ __launch_bounds__(256) void proj_kernel(
    const float* __restrict__ Q, const float* __restrict__ Km, const float* __restrict__ V,
    const float* __restrict__ Wq, const float* __restrict__ Wk, const float* __restrict__ Wv,
    const float* __restrict__ Wr,
    float* __restrict__ qT, float* __restrict__ kT, float* __restrict__ vT,
    float* __restrict__ coeff)
{
    const int z = blockIdx.z;
    const float* __restrict__ X = (z == 0) ? Q : (z == 1) ? Km : V;
    const float* __restrict__ W = (z == 0) ? Wq : (z == 1) ? Wk : Wv;
    float* __restrict__ dst     = (z == 0) ? qT : (z == 1) ? kT : vT;

    const int n0 = blockIdx.x * 64;
    const int o0 = blockIdx.y * 64;
    const int tid = threadIdx.x;
    const int tx = tid & 15, ty = tid >> 4;

    __shared__ float Xs[32][68];
    __shared__ float Ws[32][68];

    float acc[4][4];
    #pragma unroll
    for (int i = 0; i < 4; ++i)
        #pragma unroll
        for (int j = 0; j < 4; ++j) acc[i][j] = 0.f;

    const int sr = tid >> 2;
    const int sc = (tid & 3) * 8;

    for (int kb = 0; kb < EDIM; kb += 32) {
        float4 a0 = *(const float4*)(X + (n0 + sr) * EDIM + kb + sc);
        float4 a1 = *(const float4*)(X + (n0 + sr) * EDIM + kb + sc + 4);
        float4 b0 = *(const float4*)(W + (o0 + sr) * EDIM + kb + sc);
        float4 b1 = *(const float4*)(W + (o0 + sr) * EDIM + kb + sc + 4);
        __syncthreads();
        Xs[sc+0][sr]=a0.x; Xs[sc+1][sr]=a0.y; Xs[sc+2][sr]=a0.z; Xs[sc+3][sr]=a0.w;
        Xs[sc+4][sr]=a1.x; Xs[sc+5][sr]=a1.y; Xs[sc+6][sr]=a1.z; Xs[sc+7][sr]=a1.w;
        Ws[sc+0][sr]=b0.x; Ws[sc+1][sr]=b0.y; Ws[sc+2][sr]=b0.z; Ws[sc+3][sr]=b0.w;
        Ws[sc+4][sr]=b1.x; Ws[sc+5][sr]=b1.y; Ws[sc+6][sr]=b1.z; Ws[sc+7][sr]=b1.w;
        __syncthreads();
        #pragma unroll
        for (int e = 0; e < 32; ++e) {
            float4 xr = *(const float4*)&Xs[e][ty*4];
            float4 wr = *(const float4*)&Ws[e][tx*4];
            acc[0][0] += xr.x*wr.x; acc[0][1] += xr.x*wr.y; acc[0][2] += xr.x*wr.z; acc[0][3] += xr.x*wr.w;
            acc[1][0] += xr.y*wr.x; acc[1][1] += xr.y*wr.y; acc[1][2] += xr.y*wr.z; acc[1][3] += xr.y*wr.w;
            acc[2][0] += xr.z*wr.x; acc[2][1] += xr.z*wr.y; acc[2][2] += xr.z*wr.z; acc[2][3] += xr.z*wr.w;
            acc[3][0] += xr.w*wr.x; acc[3][1] += xr.w*wr.y; acc[3][2] += xr.w*wr.z; acc[3][3] += xr.w*wr.w;
        }
    }

    const int h  = (o0 >> 5) + (tx >> 3);
    const int d0 = (tx & 7) * 4;
    #pragma unroll
    for (int i = 0; i < 4; ++i) {
        const int n = n0 + ty*4 + i;
        float4 r; r.x = acc[i][0]; r.y = acc[i][1]; r.z = acc[i][2]; r.w = acc[i][3];
        *(float4*)(dst + h*(LDIM*DDIM) + n*DDIM + d0) = r;
    }

    if (z == 0) {
        const int o = o0 + tx*4;
        const float wr0 = Wr[o+0], wr1 = Wr[o+1], wr2 = Wr[o+2], wr3 = Wr[o+3];
        #pragma unroll
        for (int i = 0; i < 4; ++i) {
            float c = acc[i][0]*wr0 + acc[i][1]*wr1 + acc[i][2]*wr2 + acc[i][3]*wr3;
            c += __shfl_xor(c, 1, 64);
            c += __shfl_xor(c, 2, 64);
            c += __shfl_xor(c, 4, 64);
            if ((tx & 7) == 0) coeff[h*LDIM + n0 + ty*4 + i] = c;
        }
    }
}

// ---------------------------------------------------------------------------
// attn_kernel: flash attention, QK^T on MFMA (split-bf16 hi/lo, 3 MFMAs per
// 16x16 tile), softmax in C/D layout, PV on VALU via transposed P in LDS.
// Block: 64 q-rows, 4 waves (one 16-row strip each). Grid (16, H, P).
// Writes unnormalized O partials + per-row (m, l); combine fused in outproj.
// ---------------------------------------------------------------------------
__global__ __launch_bounds__(256, 4) void attn_kernel(
    const float* __restrict__ qT, const float* __restrict__ kT, const float* __restrict__ vT,
    const float* __restrict__ coeff, const float* __restrict__ pos,
    float* __restrict__ Op, float* __restrict__ Mp, float* __restrict__ Lp, int nkt)
{
    const int h   = blockIdx.y;
    const int q0  = blockIdx.x * 64;
    const int p   = blockIdx.z;
    const int kt0 = p * nkt * 64;
    const int tid  = threadIdx.x;
    const int wave = tid >> 6;
    const int lane = tid & 63;
    const int n    = lane & 15;     // MFMA col index / q-row index (A operand)
    const int quad = lane >> 4;
    const int qs0  = wave * 16;     // this wave's q-row strip

    __shared__ __align__(16) short khi[4*64*8];  // B-frag layout, 4 col-tiles
    __shared__ __align__(16) short klo[4*64*8];
    __shared__ float vs[64][36];                 // [c][d]
    __shared__ float ps_t[64][68];               // [c][q]  (float4 rw, aligned)
    __shared__ float alph[64];                   // per-row rescale, per k-tile
    __shared__ float pk[64];

    // ---- Q fragments (A layout: A[m=lane&15][k=quad*8+j]) — loaded once ----
    short8 qhi, qlo;
    {
        const float* qp = qT + (h*LDIM + q0 + qs0 + n) * DDIM + quad*8;
        float4 qa = *(const float4*)qp;
        float4 qb = *(const float4*)(qp + 4);
        float v[8] = {qa.x,qa.y,qa.z,qa.w, qb.x,qb.y,qb.z,qb.w};
        #pragma unroll
        for (int j = 0; j < 8; ++j) {
            unsigned short hh = bf16h(v[j]);
            qhi[j] = (short)hh;
            qlo[j] = (short)bf16h(v[j] - bf16tof(hh));
        }
    }

    // ---- per-row bias constants (rows qs0+4*quad+i, i=0..3, C/D layout) ----
    float pq[4], cq[4];
    #pragma unroll
    for (int i = 0; i < 4; ++i) {
        const int r = q0 + qs0 + 4*quad + i;
        pq[i] = pos[r];
        cq[i] = coeff[h*LDIM + r] * 0.0625f;   // pre-divide by sqrt(E)=16
    }

    float m[4], l[4];
    #pragma unroll
    for (int i = 0; i < 4; ++i) { m[i] = -INFINITY; l[i] = 0.f; }

    // PV-role mapping: thread handles rows pr0..pr0+3, cols dg2..dg2+1
    const int pr0 = (tid >> 4) * 4;
    const int dg2 = (tid & 15) * 2;
    float o[4][2];
    #pragma unroll
    for (int i = 0; i < 4; ++i) { o[i][0] = 0.f; o[i][1] = 0.f; }

    const int cS = tid >> 2;          // staging: k/v row 0..63
    const int dq = tid & 3;           // staging: d-chunk 0..3 (8 d each)
    const int lane2 = (cS & 15) | (dq << 4);
    const int gS = cS >> 4;

    for (int t = 0; t < nkt; ++t) {
        const int kt = kt0 + t * 64;
        // ---- global loads (regs) ----
        const float* kp = kT + (h*LDIM + kt + cS) * DDIM + dq*8;
        float4 k0 = *(const float4*)kp;
        float4 k1 = *(const float4*)(kp + 4);
        const float* vp = vT + (h*LDIM + kt + cS) * DDIM + dq*8;
        float4 v0 = *(const float4*)vp;
        float4 v1 = *(const float4*)(vp + 4);

        __syncthreads();   // (A) prev iter's khi/vs/ps_t consumers done

        // ---- stage K as split-bf16 B-frags (lane-contiguous 16B runs) ----
        {
            float kv[8] = {k0.x,k0.y,k0.z,k0.w, k1.x,k1.y,k1.z,k1.w};
            short8 hi8, lo8;
            #pragma unroll
            for (int j = 0; j < 8; ++j) {
                unsigned short hh = bf16h(kv[j]);
                hi8[j] = (short)hh;
                lo8[j] = (short)bf16h(kv[j] - bf16tof(hh));
            }
            *((short8*)&khi[(gS*64 + lane2)*8]) = hi8;
            *((short8*)&klo[(gS*64 + lane2)*8]) = lo8;
        }
        *(float4*)&vs[cS][dq*8]     = v0;
        *(float4*)&vs[cS][dq*8 + 4] = v1;
        if (tid < 64) pk[tid] = pos[kt + tid];
        __syncthreads();   // (B) staging visible

        // ---- S = QK^T via 3-term split-bf16 MFMA, 4 col-tiles ----
        f32x4 Sf[4];
        #pragma unroll
        for (int t4 = 0; t4 < 4; ++t4) {
            short8 bhi = *((const short8*)&khi[(t4*64 + lane)*8]);
            short8 blo = *((const short8*)&klo[(t4*64 + lane)*8]);
            f32x4 acc = {0.f, 0.f, 0.f, 0.f};
            acc = __builtin_amdgcn_mfma_f32_16x16x32_bf16(qlo, bhi, acc, 0, 0, 0);
            acc = __builtin_amdgcn_mfma_f32_16x16x32_bf16(qhi, blo, acc, 0, 0, 0);
            acc = __builtin_amdgcn_mfma_f32_16x16x32_bf16(qhi, bhi, acc, 0, 0, 0);
            Sf[t4] = acc;
        }

        // ---- bias + online softmax (C/D layout: row=4*quad+i, col=16*t4+n) --
        float ev[4][4];
        float rmax[4] = {-INFINITY, -INFINITY, -INFINITY, -INFINITY};
        #pragma unroll
        for (int t4 = 0; t4 < 4; ++t4) {
            const float pkt = pk[16*t4 + n];
            #pragma unroll
            for (int i = 0; i < 4; ++i) {
                float s = fmaf(Sf[t4][i], 0.0625f, cq[i] * __logf(fabsf(pq[i] - pkt) + 1.f));
                ev[t4][i] = s;
                rmax[i] = fmaxf(rmax[i], s);
            }
        }
        #pragma unroll
        for (int off = 1; off < 16; off <<= 1)
            #pragma unroll
            for (int i = 0; i < 4; ++i)
                rmax[i] = fmaxf(rmax[i], __shfl_xor(rmax[i], off, 64));

        float al[4], rsum[4];
        #pragma unroll
        for (int i = 0; i < 4; ++i) {
            const float mn = fmaxf(m[i], rmax[i]);
            al[i] = __expf(m[i] - mn);
            m[i] = mn;
            rsum[i] = 0.f;
        }
        #pragma unroll
        for (int t4 = 0; t4 < 4; ++t4)
            #pragma unroll
            for (int i = 0; i < 4; ++i) {
                float e = __expf(ev[t4][i] - m[i]);
                ev[t4][i] = e;
                rsum[i] += e;
            }
        #pragma unroll
        for (int off = 1; off < 16; off <<= 1)
            #pragma unroll
            for (int i = 0; i < 4; ++i)
                rsum[i] += __shfl_xor(rsum[i], off, 64);
        #pragma unroll
        for (int i = 0; i < 4; ++i) l[i] = l[i]*al[i] + rsum[i];

        if (n == 0) {
            #pragma unroll
            for (int i = 0; i < 4; ++i) alph[qs0 + 4*quad + i] = al[i];
        }
        // ---- write P transposed: lane's 4 rows are consecutive -> float4 ----
        #pragma unroll
        for (int t4 = 0; t4 < 4; ++t4) {
            float4 w; w.x = ev[t4][0]; w.y = ev[t4][1]; w.z = ev[t4][2]; w.w = ev[t4][3];
            *(float4*)&ps_t[16*t4 + n][qs0 + 4*quad] = w;
        }
        __syncthreads();   // (C) ps_t/alph visible

        // ---- PV (VALU): o[4 rows][2 d] over 64 cols ----
        {
            float4 a4 = *(const float4*)&alph[pr0];
            o[0][0]*=a4.x; o[0][1]*=a4.x; o[1][0]*=a4.y; o[1][1]*=a4.y;
            o[2][0]*=a4.z; o[2][1]*=a4.z; o[3][0]*=a4.w; o[3][1]*=a4.w;
        }
        #pragma unroll 4
        for (int c = 0; c < 64; ++c) {
            float4 p4 = *(const float4*)&ps_t[c][pr0];
            float2 v2 = *(const float2*)&vs[c][dg2];
            o[0][0] += p4.x*v2.x; o[0][1] += p4.x*v2.y;
            o[1][0] += p4.y*v2.x; o[1][1] += p4.y*v2.y;
            o[2][0] += p4.z*v2.x; o[2][1] += p4.z*v2.y;
            o[3][0] += p4.w*v2.x; o[3][1] += p4.w*v2.y;
        }
    }

    // ---- write partials ----
    const int ph = p * HDIM + h;
    #pragma unroll
    for (int i = 0; i < 4; ++i) {
        float2 w; w.x = o[i][0]; w.y = o[i][1];
        *(float2*)(Op + ((size_t)ph*LDIM + q0 + pr0 + i)*DDIM + dg2) = w;
    }
    if (n == 0) {
        #pragma unroll
        for (int i = 0; i < 4; ++i) {
            const int r = q0 + qs0 + 4*quad + i;
            Mp[ph*LDIM + r] = m[i];
            Lp[ph*LDIM + r] = l[i];
        }
    }
}

// ---------------------------------------------------------------------------
// outproj_kernel: out(L,E) = A(L,E) @ Wo(E,E)^T + bo; A reconstructed on the
// fly from up to 8 attention partials (combine fused into staging).
// 32x32 tiles -> grid (32, 8) = 256 blocks, micro 2x2.
// ---------------------------------------------------------------------------
__global__ __launch_bounds__(256) void outproj_kernel(
    const float* __restrict__ Op, const float* __restrict__ Mp, const float* __restrict__ Lp,
    int P, const float* __restrict__ Wo, const float* __restrict__ bo, float* __restrict__ out)
{
    const int n0 = blockIdx.x * 32;
    const int o0 = blockIdx.y * 32;
    const int tid = threadIdx.x;
    const int tx = tid & 15, ty = tid >> 4;

    __shared__ float Xs[32][34];
    __shared__ float Ws[32][34];
    __shared__ float scl[32][8];

    float acc[2][2] = {{0.f,0.f},{0.f,0.f}};

    const int sn = tid >> 3;
    const int sc4 = (tid & 7) * 4;

    for (int kb = 0; kb < EDIM; kb += 32) {
        const int h = kb >> 5;
        if (tid < 32) {
            const int nr = n0 + tid;
            float mv[8], lv[8];
            float mx = -INFINITY;
            #pragma unroll
            for (int p = 0; p < 8; ++p) if (p < P) {
                mv[p] = Mp[(p*HDIM + h)*LDIM + nr];
                lv[p] = Lp[(p*HDIM + h)*LDIM + nr];
                mx = fmaxf(mx, mv[p]);
            }
            float s = 0.f;
            #pragma unroll
            for (int p = 0; p < 8; ++p) if (p < P) {
                float a = __expf(mv[p] - mx);
                mv[p] = a;
                s += a * lv[p];
            }
            const float invs = 1.f / s;
            #pragma unroll
            for (int p = 0; p < 8; ++p) scl[tid][p] = (p < P) ? mv[p]*invs : 0.f;
        }
        __syncthreads();   // scl ready; prev iter inner reads done

        {
            const float* ob = Op + ((size_t)h*LDIM + n0 + sn)*DDIM + sc4;
            float4 x; x.x = x.y = x.z = x.w = 0.f;
            #pragma unroll
            for (int p = 0; p < 8; ++p) if (p < P) {
                const float sp = scl[sn][p];
                float4 xp = *(const float4*)(ob + (size_t)p*HDIM*LDIM*DDIM);
                x.x += sp*xp.x; x.y += sp*xp.y; x.z += sp*xp.z; x.w += sp*xp.w;
            }
            float4 w = *(const float4*)(Wo + (o0 + sn)*EDIM + kb + sc4);
            Xs[sc4+0][sn]=x.x; Xs[sc4+1][sn]=x.y; Xs[sc4+2][sn]=x.z; Xs[sc4+3][sn]=x.w;
            Ws[sc4+0][sn]=w.x; Ws[sc4+1][sn]=w.y; Ws[sc4+2][sn]=w.z; Ws[sc4+3][sn]=w.w;
        }
        __syncthreads();

        #pragma unroll
        for (int e = 0; e < 32; ++e) {
            float2 x2 = *(const float2*)&Xs[e][ty*2];
            float2 w2 = *(const float2*)&Ws[e][tx*2];
            acc[0][0] += x2.x*w2.x; acc[0][1] += x2.x*w2.y;
            acc[1][0] += x2.y*w2.x; acc[1][1] += x2.y*w2.y;
        }
    }

    const int oo = o0 + tx*2;
    float2 bias = *(const float2*)(bo + oo);
    #pragma unroll
    for (int i = 0; i < 2; ++i) {
        const int nn = n0 + ty*2 + i;
        float2 r; r.x = acc[i][0] + bias.x; r.y = acc[i][1] + bias.y;
        *(float2*)(out + nn*EDIM + oo) = r;
    }
}

// ---------------------------------------------------------------------------
extern "C" void kernel_launch(void* const* d_in, const int* in_sizes, int n_in,
                              void* d_out, int out_size, void* d_ws, size_t ws_size,
                              hipStream_t stream) {
    const float* V   = (const float*)d_in[0];
    const float* K   = (const float*)d_in[1];
    const float* Q   = (const float*)d_in[2];
    const float* pos = (const float*)d_in[3];
    const float* Wq  = (const float*)d_in[4];
    const float* Wk  = (const float*)d_in[5];
    const float* Wv  = (const float*)d_in[6];
    const float* Wr  = (const float*)d_in[7];
    const float* Wo  = (const float*)d_in[8];
    const float* bo  = (const float*)d_in[9];
    float* out = (float*)d_out;
    float* ws  = (float*)d_ws;

    // ws floats: base = qT/kT/vT (3*262144) + coeff (8192); per partial:
    // Op 262144 + Mp 8192 + Lp 8192.
    auto need = [](int P) -> size_t {
        return (size_t)(794624 + P*278528) * 4;
    };
    int P = 2;
    if (ws_size >= need(8)) P = 8;
    else if (ws_size >= need(4)) P = 4;

    float* qT    = ws;
    float* kT    = ws + 262144;
    float* vT    = ws + 524288;
    float* coeff = ws + 786432;
    float* Op    = ws + 794624;
    float* Mp    = Op + (size_t)P * 262144;
    float* Lp    = Mp + (size_t)P * 8192;

    proj_kernel   <<<dim3(16, 4, 3), 256, 0, stream>>>(Q, K, V, Wq, Wk, Wv, Wr, qT, kT, vT, coeff);
    attn_kernel   <<<dim3(16, 8, P), 256, 0, stream>>>(qT, kT, vT, coeff, pos, Op, Mp, Lp, 16 / P);
    outproj_kernel<<<dim3(32, 8),    256, 0, stream>>>(Op, Mp, Lp, P, Wo, bo, out);
}

// Round 4
// 122.745 us; speedup vs baseline: 1.3006x; 1.2092x over previous
//
#include <hip/hip_runtime.h>
#include <math.h>

#define EDIM 256
#define LDIM 1024
#define HDIM 8
#define DDIM 32

typedef __attribute__((ext_vector_type(8))) short short8;
typedef __attribute__((ext_vector_type(4))) float f32x4;

__device__ inline unsigned short bf16h(float x) {
    unsigned u = __float_as_uint(x);
    return (unsigned short)((u + 0x7fff + ((u >> 16) & 1)) >> 16);   // RNE
}
__device__ inline float bf16tof(unsigned short h) {
    return __uint_as_float(((unsigned)h) << 16);
}

// ---------------------------------------------------------------------------
// proj_kernel: dst(H,L,D) = X(L,E) @ W(E,E)^T, one GEMM per blockIdx.z.
// 32x32 tile, 2x2 micro, grid (32,8,3)=768 blocks (3 blocks/CU) for latency
// hiding. Software-pipelined: kb+1 global loads issued before kb compute.
// z==0 fuses coeff[h][n] = sum_d q[n,h,d]*Wr[h*32+d] (o-tile == one head).
// ---------------------------------------------------------------------------
__global__ __launch_bounds__(256) void proj_kernel(
    const float* __restrict__ Q, const float* __restrict__ Km, const float* __restrict__ V,
    const float* __restrict__ Wq, const float* __restrict__ Wk, const float* __restrict__ Wv,
    const float* __restrict__ Wr,
    float* __restrict__ qT, float* __restrict__ kT, float* __restrict__ vT,
    float* __restrict__ coeff)
{
    const int z = blockIdx.z;
    const float* __restrict__ X = (z == 0) ? Q : (z == 1) ? Km : V;
    const float* __restrict__ W = (z == 0) ? Wq : (z == 1) ? Wk : Wv;
    float* __restrict__ dst     = (z == 0) ? qT : (z == 1) ? kT : vT;

    const int n0 = blockIdx.x * 32;
    const int o0 = blockIdx.y * 32;       // one head (o0 = h*32)
    const int tid = threadIdx.x;
    const int tx = tid & 15, ty = tid >> 4;

    __shared__ float Xs[32][34];   // [e][n]
    __shared__ float Ws[32][34];   // [e][o]

    float acc[2][2] = {{0.f,0.f},{0.f,0.f}};

    const int sn  = tid >> 3;        // 0..31 tile row
    const int sc4 = (tid & 7) * 4;   // 0..28 k-chunk

    float4 xa = *(const float4*)(X + (n0 + sn) * EDIM + sc4);
    float4 wa = *(const float4*)(W + (o0 + sn) * EDIM + sc4);

    for (int kb = 0; kb < EDIM; kb += 32) {
        __syncthreads();   // previous compute done, LDS free
        Xs[sc4+0][sn]=xa.x; Xs[sc4+1][sn]=xa.y; Xs[sc4+2][sn]=xa.z; Xs[sc4+3][sn]=xa.w;
        Ws[sc4+0][sn]=wa.x; Ws[sc4+1][sn]=wa.y; Ws[sc4+2][sn]=wa.z; Ws[sc4+3][sn]=wa.w;
        float4 xn, wn;
        if (kb + 32 < EDIM) {
            xn = *(const float4*)(X + (n0 + sn) * EDIM + kb + 32 + sc4);
            wn = *(const float4*)(W + (o0 + sn) * EDIM + kb + 32 + sc4);
        }
        __syncthreads();   // staged
        #pragma unroll
        for (int e = 0; e < 32; ++e) {
            float2 x2 = *(const float2*)&Xs[e][ty*2];
            float2 w2 = *(const float2*)&Ws[e][tx*2];
            acc[0][0] += x2.x*w2.x; acc[0][1] += x2.x*w2.y;
            acc[1][0] += x2.y*w2.x; acc[1][1] += x2.y*w2.y;
        }
        xa = xn; wa = wn;
    }

    // write to (H, L, D): h = o0/32, d = tx*2
    const int h = o0 >> 5;
    #pragma unroll
    for (int i = 0; i < 2; ++i) {
        const int n = n0 + ty*2 + i;
        float2 r; r.x = acc[i][0]; r.y = acc[i][1];
        *(float2*)(dst + h*(LDIM*DDIM) + n*DDIM + tx*2) = r;
    }

    // fused coeff epilogue (q projection only): reduce over the 16 tx lanes
    if (z == 0) {
        const float wr0 = Wr[o0 + tx*2], wr1 = Wr[o0 + tx*2 + 1];
        #pragma unroll
        for (int i = 0; i < 2; ++i) {
            float c = acc[i][0]*wr0 + acc[i][1]*wr1;
            c += __shfl_xor(c, 1, 64);
            c += __shfl_xor(c, 2, 64);
            c += __shfl_xor(c, 4, 64);
            c += __shfl_xor(c, 8, 64);
            if (tx == 0) coeff[h*LDIM + n0 + ty*2 + i] = c;
        }
    }
}

// ---------------------------------------------------------------------------
// attn_kernel: flash attention, QK^T on MFMA (split-bf16 hi/lo, 3 MFMAs per
// 16x16 tile), softmax in C/D layout, PV on VALU via transposed P in LDS.
// Block: 64 q-rows, 4 waves. Grid (16, H, P). Prefetches next k/v tile
// during compute. Writes unnormalized O partials + (m, l).
// ---------------------------------------------------------------------------
__global__ __launch_bounds__(256, 4) void attn_kernel(
    const float* __restrict__ qT, const float* __restrict__ kT, const float* __restrict__ vT,
    const float* __restrict__ coeff, const float* __restrict__ pos,
    float* __restrict__ Op, float* __restrict__ Mp, float* __restrict__ Lp, int nkt)
{
    const int h   = blockIdx.y;
    const int q0  = blockIdx.x * 64;
    const int p   = blockIdx.z;
    const int kt0 = p * nkt * 64;
    const int tid  = threadIdx.x;
    const int wave = tid >> 6;
    const int lane = tid & 63;
    const int n    = lane & 15;
    const int quad = lane >> 4;
    const int qs0  = wave * 16;

    __shared__ __align__(16) short khi[4*64*8];
    __shared__ __align__(16) short klo[4*64*8];
    __shared__ float vs[64][36];
    __shared__ float ps_t[64][68];
    __shared__ float alph[64];
    __shared__ float pk[64];

    // ---- Q fragments (A layout) — loaded once ----
    short8 qhi, qlo;
    {
        const float* qp = qT + (h*LDIM + q0 + qs0 + n) * DDIM + quad*8;
        float4 qa = *(const float4*)qp;
        float4 qb = *(const float4*)(qp + 4);
        float v[8] = {qa.x,qa.y,qa.z,qa.w, qb.x,qb.y,qb.z,qb.w};
        #pragma unroll
        for (int j = 0; j < 8; ++j) {
            unsigned short hh = bf16h(v[j]);
            qhi[j] = (short)hh;
            qlo[j] = (short)bf16h(v[j] - bf16tof(hh));
        }
    }

    float pq[4], cq[4];
    #pragma unroll
    for (int i = 0; i < 4; ++i) {
        const int r = q0 + qs0 + 4*quad + i;
        pq[i] = pos[r];
        cq[i] = coeff[h*LDIM + r] * 0.0625f;
    }

    float m[4], l[4];
    #pragma unroll
    for (int i = 0; i < 4; ++i) { m[i] = -INFINITY; l[i] = 0.f; }

    const int pr0 = (tid >> 4) * 4;
    const int dg2 = (tid & 15) * 2;
    float o[4][2];
    #pragma unroll
    for (int i = 0; i < 4; ++i) { o[i][0] = 0.f; o[i][1] = 0.f; }

    const int cS = tid >> 2;
    const int dq = tid & 3;
    const int lane2 = (cS & 15) | (dq << 4);
    const int gS = cS >> 4;

    // preload tile 0
    float4 k0c, k1c, v0c, v1c; float pkc = 0.f;
    {
        const float* kp = kT + (h*LDIM + kt0 + cS) * DDIM + dq*8;
        k0c = *(const float4*)kp; k1c = *(const float4*)(kp + 4);
        const float* vp = vT + (h*LDIM + kt0 + cS) * DDIM + dq*8;
        v0c = *(const float4*)vp; v1c = *(const float4*)(vp + 4);
        if (tid < 64) pkc = pos[kt0 + tid];
    }

    for (int t = 0; t < nkt; ++t) {
        __syncthreads();   // (A) prev consumers done

        {   // stage current regs as split-bf16 B-frags + vs + pk
            float kv[8] = {k0c.x,k0c.y,k0c.z,k0c.w, k1c.x,k1c.y,k1c.z,k1c.w};
            short8 hi8, lo8;
            #pragma unroll
            for (int j = 0; j < 8; ++j) {
                unsigned short hh = bf16h(kv[j]);
                hi8[j] = (short)hh;
                lo8[j] = (short)bf16h(kv[j] - bf16tof(hh));
            }
            *((short8*)&khi[(gS*64 + lane2)*8]) = hi8;
            *((short8*)&klo[(gS*64 + lane2)*8]) = lo8;
            *(float4*)&vs[cS][dq*8]     = v0c;
            *(float4*)&vs[cS][dq*8 + 4] = v1c;
            if (tid < 64) pk[tid] = pkc;
        }

        // prefetch next tile (overlaps with compute below)
        float4 k0n, k1n, v0n, v1n; float pkn = 0.f;
        if (t + 1 < nkt) {
            const int kt = kt0 + (t+1) * 64;
            const float* kp = kT + (h*LDIM + kt + cS) * DDIM + dq*8;
            k0n = *(const float4*)kp; k1n = *(const float4*)(kp + 4);
            const float* vp = vT + (h*LDIM + kt + cS) * DDIM + dq*8;
            v0n = *(const float4*)vp; v1n = *(const float4*)(vp + 4);
            if (tid < 64) pkn = pos[kt + tid];
        }
        __syncthreads();   // (B) staging visible

        // ---- S = QK^T via 3-term split-bf16 MFMA, 4 col-tiles ----
        f32x4 Sf[4];
        #pragma unroll
        for (int t4 = 0; t4 < 4; ++t4) {
            short8 bhi = *((const short8*)&khi[(t4*64 + lane)*8]);
            short8 blo = *((const short8*)&klo[(t4*64 + lane)*8]);
            f32x4 acc = {0.f, 0.f, 0.f, 0.f};
            acc = __builtin_amdgcn_mfma_f32_16x16x32_bf16(qlo, bhi, acc, 0, 0, 0);
            acc = __builtin_amdgcn_mfma_f32_16x16x32_bf16(qhi, blo, acc, 0, 0, 0);
            acc = __builtin_amdgcn_mfma_f32_16x16x32_bf16(qhi, bhi, acc, 0, 0, 0);
            Sf[t4] = acc;
        }

        // ---- bias + online softmax ----
        float ev[4][4];
        float rmax[4] = {-INFINITY, -INFINITY, -INFINITY, -INFINITY};
        #pragma unroll
        for (int t4 = 0; t4 < 4; ++t4) {
            const float pkt = pk[16*t4 + n];
            #pragma unroll
            for (int i = 0; i < 4; ++i) {
                float s = fmaf(Sf[t4][i], 0.0625f, cq[i] * __logf(fabsf(pq[i] - pkt) + 1.f));
                ev[t4][i] = s;
                rmax[i] = fmaxf(rmax[i], s);
            }
        }
        #pragma unroll
        for (int off = 1; off < 16; off <<= 1)
            #pragma unroll
            for (int i = 0; i < 4; ++i)
                rmax[i] = fmaxf(rmax[i], __shfl_xor(rmax[i], off, 64));

        float al[4], rsum[4];
        #pragma unroll
        for (int i = 0; i < 4; ++i) {
            const float mn = fmaxf(m[i], rmax[i]);
            al[i] = __expf(m[i] - mn);
            m[i] = mn;
            rsum[i] = 0.f;
        }
        #pragma unroll
        for (int t4 = 0; t4 < 4; ++t4)
            #pragma unroll
            for (int i = 0; i < 4; ++i) {
                float e = __expf(ev[t4][i] - m[i]);
                ev[t4][i] = e;
                rsum[i] += e;
            }
        #pragma unroll
        for (int off = 1; off < 16; off <<= 1)
            #pragma unroll
            for (int i = 0; i < 4; ++i)
                rsum[i] += __shfl_xor(rsum[i], off, 64);
        #pragma unroll
        for (int i = 0; i < 4; ++i) l[i] = l[i]*al[i] + rsum[i];

        if (n == 0) {
            #pragma unroll
            for (int i = 0; i < 4; ++i) alph[qs0 + 4*quad + i] = al[i];
        }
        #pragma unroll
        for (int t4 = 0; t4 < 4; ++t4) {
            float4 w; w.x = ev[t4][0]; w.y = ev[t4][1]; w.z = ev[t4][2]; w.w = ev[t4][3];
            *(float4*)&ps_t[16*t4 + n][qs0 + 4*quad] = w;
        }
        __syncthreads();   // (C) ps_t/alph visible

        {
            float4 a4 = *(const float4*)&alph[pr0];
            o[0][0]*=a4.x; o[0][1]*=a4.x; o[1][0]*=a4.y; o[1][1]*=a4.y;
            o[2][0]*=a4.z; o[2][1]*=a4.z; o[3][0]*=a4.w; o[3][1]*=a4.w;
        }
        #pragma unroll 4
        for (int c = 0; c < 64; ++c) {
            float4 p4 = *(const float4*)&ps_t[c][pr0];
            float2 v2 = *(const float2*)&vs[c][dg2];
            o[0][0] += p4.x*v2.x; o[0][1] += p4.x*v2.y;
            o[1][0] += p4.y*v2.x; o[1][1] += p4.y*v2.y;
            o[2][0] += p4.z*v2.x; o[2][1] += p4.z*v2.y;
            o[3][0] += p4.w*v2.x; o[3][1] += p4.w*v2.y;
        }

        k0c = k0n; k1c = k1n; v0c = v0n; v1c = v1n; pkc = pkn;
    }

    const int ph = p * HDIM + h;
    #pragma unroll
    for (int i = 0; i < 4; ++i) {
        float2 w; w.x = o[i][0]; w.y = o[i][1];
        *(float2*)(Op + ((size_t)ph*LDIM + q0 + pr0 + i)*DDIM + dg2) = w;
    }
    if (n == 0) {
        #pragma unroll
        for (int i = 0; i < 4; ++i) {
            const int r = q0 + qs0 + 4*quad + i;
            Mp[ph*LDIM + r] = m[i];
            Lp[ph*LDIM + r] = l[i];
        }
    }
}

// ---------------------------------------------------------------------------
// combine_kernel: A(L,E) = normalized combine of P attention partials.
// 65536 threads (256 blocks), one float4 of A per thread. Mp/Lp loads are
// wave-broadcast (all 64 lanes share a row); Op loads coalesced per head.
// ---------------------------------------------------------------------------
__global__ __launch_bounds__(256) void combine_kernel(
    const float* __restrict__ Op, const float* __restrict__ Mp, const float* __restrict__ Lp,
    int P, float* __restrict__ A)
{
    const int idx = blockIdx.x * 256 + threadIdx.x;   // 0..65535
    const int n  = idx >> 6;          // row 0..1023
    const int e4 = (idx & 63) * 4;    // 0..252
    const int h  = e4 >> 5;
    const int d  = e4 & 31;

    float mv[8], lv[8];
    float mx = -INFINITY;
    #pragma unroll
    for (int p = 0; p < 8; ++p) if (p < P) {
        mv[p] = Mp[(p*HDIM + h)*LDIM + n];
        lv[p] = Lp[(p*HDIM + h)*LDIM + n];
        mx = fmaxf(mx, mv[p]);
    }
    float s = 0.f;
    #pragma unroll
    for (int p = 0; p < 8; ++p) if (p < P) {
        float a = __expf(mv[p] - mx);
        mv[p] = a;
        s += a * lv[p];
    }
    const float inv = 1.f / s;

    float4 x; x.x = x.y = x.z = x.w = 0.f;
    #pragma unroll
    for (int p = 0; p < 8; ++p) if (p < P) {
        const float sp = mv[p] * inv;
        float4 xp = *(const float4*)(Op + ((size_t)(p*HDIM + h)*LDIM + n)*DDIM + d);
        x.x += sp*xp.x; x.y += sp*xp.y; x.z += sp*xp.z; x.w += sp*xp.w;
    }
    *(float4*)(A + n*EDIM + e4) = x;
}

// ---------------------------------------------------------------------------
// outproj_kernel: out(L,E) = A(L,E) @ Wo(E,E)^T + bo. 32x32 tiles, 2x2 micro,
// grid (32,8)=256 blocks, software-pipelined like proj_kernel.
// ---------------------------------------------------------------------------
__global__ __launch_bounds__(256) void outproj_kernel(
    const float* __restrict__ A, const float* __restrict__ Wo,
    const float* __restrict__ bo, float* __restrict__ out)
{
    const int n0 = blockIdx.x * 32;
    const int o0 = blockIdx.y * 32;
    const int tid = threadIdx.x;
    const int tx = tid & 15, ty = tid >> 4;

    __shared__ float Xs[32][34];
    __shared__ float Ws[32][34];

    float acc[2][2] = {{0.f,0.f},{0.f,0.f}};

    const int sn  = tid >> 3;
    const int sc4 = (tid & 7) * 4;

    float4 xa = *(const float4*)(A  + (n0 + sn) * EDIM + sc4);
    float4 wa = *(const float4*)(Wo + (o0 + sn) * EDIM + sc4);

    for (int kb = 0; kb < EDIM; kb += 32) {
        __syncthreads();
        Xs[sc4+0][sn]=xa.x; Xs[sc4+1][sn]=xa.y; Xs[sc4+2][sn]=xa.z; Xs[sc4+3][sn]=xa.w;
        Ws[sc4+0][sn]=wa.x; Ws[sc4+1][sn]=wa.y; Ws[sc4+2][sn]=wa.z; Ws[sc4+3][sn]=wa.w;
        float4 xn, wn;
        if (kb + 32 < EDIM) {
            xn = *(const float4*)(A  + (n0 + sn) * EDIM + kb + 32 + sc4);
            wn = *(const float4*)(Wo + (o0 + sn) * EDIM + kb + 32 + sc4);
        }
        __syncthreads();
        #pragma unroll
        for (int e = 0; e < 32; ++e) {
            float2 x2 = *(const float2*)&Xs[e][ty*2];
            float2 w2 = *(const float2*)&Ws[e][tx*2];
            acc[0][0] += x2.x*w2.x; acc[0][1] += x2.x*w2.y;
            acc[1][0] += x2.y*w2.x; acc[1][1] += x2.y*w2.y;
        }
        xa = xn; wa = wn;
    }

    const int oo = o0 + tx*2;
    float2 bias = *(const float2*)(bo + oo);
    #pragma unroll
    for (int i = 0; i < 2; ++i) {
        const int nn = n0 + ty*2 + i;
        float2 r; r.x = acc[i][0] + bias.x; r.y = acc[i][1] + bias.y;
        *(float2*)(out + nn*EDIM + oo) = r;
    }
}

// ---------------------------------------------------------------------------
extern "C" void kernel_launch(void* const* d_in, const int* in_sizes, int n_in,
                              void* d_out, int out_size, void* d_ws, size_t ws_size,
                              hipStream_t stream) {
    const float* V   = (const float*)d_in[0];
    const float* K   = (const float*)d_in[1];
    const float* Q   = (const float*)d_in[2];
    const float* pos = (const float*)d_in[3];
    const float* Wq  = (const float*)d_in[4];
    const float* Wk  = (const float*)d_in[5];
    const float* Wv  = (const float*)d_in[6];
    const float* Wr  = (const float*)d_in[7];
    const float* Wo  = (const float*)d_in[8];
    const float* bo  = (const float*)d_in[9];
    float* out = (float*)d_out;
    float* ws  = (float*)d_ws;

    auto need = [](int P) -> size_t {
        return (size_t)(794624 + P*278528) * 4;
    };
    int P = 2;
    if (ws_size >= need(8)) P = 8;
    else if (ws_size >= need(4)) P = 4;

    float* qT    = ws;                      // also reused as A after attn
    float* kT    = ws + 262144;
    float* vT    = ws + 524288;
    float* coeff = ws + 786432;
    float* Op    = ws + 794624;
    float* Mp    = Op + (size_t)P * 262144;
    float* Lp    = Mp + (size_t)P * 8192;
    float* A     = qT;                      // qT dead after attn_kernel

    proj_kernel   <<<dim3(32, 8, 3), 256, 0, stream>>>(Q, K, V, Wq, Wk, Wv, Wr, qT, kT, vT, coeff);
    attn_kernel   <<<dim3(16, 8, P), 256, 0, stream>>>(qT, kT, vT, coeff, pos, Op, Mp, Lp, 16 / P);
    combine_kernel<<<dim3(256),      256, 0, stream>>>(Op, Mp, Lp, P, A);
    outproj_kernel<<<dim3(32, 8),    256, 0, stream>>>(A, Wo, bo, out);
}